// Round 9
// baseline (1129.479 us; speedup 1.0000x reference)
//
#include <hip/hip_runtime.h>
#include <hip/hip_bf16.h>

// Problem constants
#define BATCH 512
#define TT 60
#define EDIM 300
#define HDIM 512
#define KREAL 812
#define KP 896           // 7 chunks of 128: emb k[0,300) pad[300,384) h k[384,896)
#define KP1 2112         // padded K for head GEMM (2053 -> 2112)
#define MDIM 256

typedef __bf16 bf16x4 __attribute__((ext_vector_type(4)));
typedef __bf16 bf16x8 __attribute__((ext_vector_type(8)));
typedef float  f32x16 __attribute__((ext_vector_type(16)));

__device__ __forceinline__ float sigm(float x) {
    return 1.0f / (1.0f + __expf(-x));
}
__device__ __forceinline__ float tanh_fast(float x) {
    float e = __expf(-2.0f * fabsf(x));
    float r = (1.0f - e) / (1.0f + e);
    return x >= 0.0f ? r : -r;
}

// ---------------------------------------------------------------------------
// Fragment layouts (bf16; a "slot" is lane*8 elems = 16B):
// Wf (weights): [cg:32][c:7][T:32][lane:64][e:8], T = j*4 + nt*2 + plane
// Xf (activations, 64-row tiles): [tile:16][s:2][kg:2][c:7][jj:4][plane:2][lane:64][e:8]
//   slot l of (tile,s,kg,c,jj,plane) = A[row = tile*64 + s*32 + (l&31)]
//                                       [k = c*128 + kg*64 + jj*16 + (l>>5)*8 + e]
// Rows are PERMUTED (sorted by seqlen desc): rowinfo[r] -> (src,b,sl).
// c_state at permuted index; h_state at ORIGINAL index (head1 reads unpermuted).
// ---------------------------------------------------------------------------

// Counting sort of the 1024 rows by seqlen descending; emits rowinfo and
// per-step active-tile counts nact[t] (64-row tiles).
__global__ __launch_bounds__(256) void sort_rows(const int* __restrict__ sl1,
                                                 const int* __restrict__ sl2,
                                                 int* __restrict__ rowinfo,
                                                 unsigned* __restrict__ nact) {
    __shared__ unsigned cnt[61];
    __shared__ unsigned off[61];
    int tid = threadIdx.x;
    if (tid < 61) cnt[tid] = 0;
    __syncthreads();
    for (int i = tid; i < 1024; i += 256) {
        int sl = (i < 512) ? sl1[i] : sl2[i - 512];
        atomicAdd(&cnt[60 - sl], 1u);
    }
    __syncthreads();
    if (tid == 0) {
        unsigned s = 0;
        for (int k = 0; k < 61; ++k) { off[k] = s; s += cnt[k]; }
        for (int t = 0; t < 60; ++t) {
            unsigned act = off[60 - t];        // #{sl > t}
            nact[t] = (act + 63) >> 6;
        }
    }
    __syncthreads();
    for (int i = tid; i < 1024; i += 256) {
        int sc = i >= 512;
        int b = i & 511;
        int sl = sc ? sl2[b] : sl1[b];
        unsigned pos = atomicAdd(&off[60 - sl], 1u);
        rowinfo[pos] = b | (sc << 15) | (sl << 20);
    }
}

// prep_w: lstm_kernel [812][2048] fp32 -> Wf (hi/lo split, k-remapped:
//   new k<300 -> kern k; 300..383 -> 0; >=384 -> kern k-84)
__global__ __launch_bounds__(256) void prep_w(const float* __restrict__ kern,
                                              __bf16* __restrict__ wf) {
    __shared__ float tile[64][65];
    int bk = blockIdx.x % 14;
    int bn = blockIdx.x / 14;
    int k0 = bk * 64, n0 = bn * 64;
    int tid = threadIdx.x;
#pragma unroll
    for (int i = 0; i < 16; ++i) {
        int id = i * 256 + tid;
        int kk = id >> 6, nn = id & 63;
        int kg = k0 + kk;
        int src = (kg < 300) ? kg : (kg >= 384 ? kg - 84 : -1);
        tile[kk][nn] = (src >= 0) ? kern[(size_t)src * 2048 + n0 + nn] : 0.0f;
    }
    __syncthreads();
    int gate = n0 >> 9;
    int nt = gate >> 1;
#pragma unroll
    for (int i = 0; i < 2; ++i) {
        int id = i * 256 + tid;          // 0..511 = nn(64) x k8(8)
        int nn = id >> 3, k8 = id & 7;
        bf16x8 hv, lv;
#pragma unroll
        for (int j = 0; j < 8; ++j) {
            float v = tile[k8 * 8 + j][nn];
            __bf16 h = (__bf16)v;
            hv[j] = h;
            lv[j] = (__bf16)(v - (float)h);
        }
        int cg = (((n0 & 511) >> 4) + (nn >> 4));
        int hc = nn & 15;
        int lzc = ((gate & 1) << 4) + hc;
        int kglob = k0 + k8 * 8;
        int c = kglob >> 7;
        int j = (kglob >> 4) & 7;
        int half = k8 & 1;
        size_t o = (size_t)cg * 114688 + c * 16384 + (j * 4 + nt * 2) * 512
                 + (half * 32 + lzc) * 8;
        *(bf16x8*)(wf + o) = hv;
        *(bf16x8*)(wf + o + 512) = lv;
    }
}

__global__ __launch_bounds__(256) void prep_w1(const float* __restrict__ W1,
                                               __bf16* __restrict__ w1h,
                                               __bf16* __restrict__ w1l) {
    __shared__ float tile[64][65];
    int bk = blockIdx.x % 33;
    int bn = blockIdx.x / 33;
    int k0 = bk * 64, n0 = bn * 64;
    int tid = threadIdx.x;
#pragma unroll
    for (int i = 0; i < 16; ++i) {
        int id = i * 256 + tid;
        int kk = id >> 6, nn = id & 63;
        int kg = k0 + kk;
        tile[kk][nn] = (kg < 2053) ? W1[(size_t)kg * MDIM + n0 + nn] : 0.0f;
    }
    __syncthreads();
#pragma unroll
    for (int i = 0; i < 2; ++i) {
        int id = i * 256 + tid;
        int nn = id >> 3, k8 = (id & 7) * 8;
        bf16x8 hv, lv;
#pragma unroll
        for (int j = 0; j < 8; ++j) {
            float v = tile[k8 + j][nn];
            __bf16 h = (__bf16)v;
            hv[j] = h;
            lv[j] = (__bf16)(v - (float)h);
        }
        size_t o = (size_t)(n0 + nn) * KP1 + k0 + k8;
        *(bf16x8*)(w1h + o) = hv;
        *(bf16x8*)(w1l + o) = lv;
    }
}

// Write one 8-elem embedding run (row rl in tile bt, run rr) into Xf frag layout
__device__ __forceinline__ void emb_unit(int tok, int rl, int rr, int bt,
                                         const float* __restrict__ emb,
                                         __bf16* Xfn) {
    const float* er = emb + (size_t)tok * EDIM + rr * 8;
    float4 f0 = *(const float4*)er;
    float4 f1 = (rr == 37) ? make_float4(0.f, 0.f, 0.f, 0.f)
                           : *(const float4*)(er + 4);
    float vv[8] = {f0.x, f0.y, f0.z, f0.w, f1.x, f1.y, f1.z, f1.w};
    bf16x8 hv, lv;
#pragma unroll
    for (int j = 0; j < 8; ++j) {
        __bf16 h = (__bf16)vv[j];
        hv[j] = h;
        lv[j] = (__bf16)(vv[j] - (float)h);
    }
    int ke = rr * 8;
    int c = ke >> 7, kl = ke & 127;
    int kg = kl >> 6, jj = (kl >> 4) & 3, half = (kl >> 3) & 1;
    int s = rl >> 5;
    size_t base = ((((size_t)bt * 2 + s) * 2 + kg) * 7 + c) * 4096 + jj * 1024
                + (half * 32 + (rl & 31)) * 8;
    *(bf16x8*)(Xfn + base) = hv;
    *(bf16x8*)(Xfn + base + 512) = lv;
}

// prep_x0: fill X0's embedding part (t=0, all tiles active). grid 512, 256 thr
__global__ __launch_bounds__(256) void prep_x0(const int* __restrict__ in1,
                                               const int* __restrict__ in2,
                                               const int* __restrict__ rowinfo,
                                               const float* __restrict__ emb,
                                               __bf16* __restrict__ Xf) {
    __shared__ int tk[64];
    int bt = blockIdx.x >> 5, cg = blockIdx.x & 31;
    int tid = threadIdx.x;
    if (tid < 64) {
        int info = rowinfo[bt * 64 + tid];
        int b = info & 511, sc = (info >> 15) & 1;
        tk[tid] = (sc ? in2 : in1)[b * TT];
    }
    __syncthreads();
    if (tid < 76) {
        int id = tid * 32 + cg;           // 0..2431 = 64 rows x 38 runs
        int rl = id / 38, rr = id - rl * 38;
        emb_unit(tk[rl], rl, rr, bt, emb, Xf);
    }
}

// ---------------------------------------------------------------------------
// One LSTM time step. grid 512 = 16 tiles (64 rows) x 32 cg (XCD-grouped),
// 256 thr = 4 waves, each wave = one k-quarter (kg, jj-half) and owns the
// FULL 64x64 output (4 acc tiles). Every A/B fragment is used by exactly one
// wave -> both operands stream DIRECTLY from global (frag layout, coalesced),
// no LDS staging, NO barriers in the k-loop. 72 KB LDS -> 2 blocks/CU.
// ---------------------------------------------------------------------------
#define ZSTR 66

__global__ __launch_bounds__(256, 2) void lstm_step(
    int t,
    const int* __restrict__ in1, const int* __restrict__ in2,
    const int* __restrict__ rowinfo, const unsigned* __restrict__ nact,
    const float* __restrict__ emb, const float* __restrict__ bias,
    const __bf16* __restrict__ wf,
    const __bf16* __restrict__ Xf, __bf16* __restrict__ Xfn,
    float* __restrict__ h_state, float* __restrict__ c_state) {

    int bx = blockIdx.x;
    int bt = bx >> 5;                                  // tile 0..15
    int cg = ((bx & 7) << 2) | ((bx >> 3) & 3);        // XCD-grouped cg
    if (bt >= (int)nact[t]) return;    // block-uniform early exit

    __shared__ float zs[4 * 64 * ZSTR];   // 67.6 KB, one plane per wave
    __shared__ __bf16 zh[4 * 64 * 8];     // 4 KB
    __shared__ int info_s[64];
    __shared__ int tk[64];

    int tid = threadIdx.x;
    int w = tid >> 6, lane = tid & 63, l31 = lane & 31;
    int kg = w & 1, jjh = w >> 1;          // k-quarter = (kg, jj-half)

    if (tid < 64) {
        int info = rowinfo[bt * 64 + tid];
        info_s[tid] = info;
        int b = info & 511, sc = (info >> 15) & 1;
        int tn = (t + 1 < TT) ? t + 1 : t;
        tk[tid] = (sc ? in2 : in1)[b * TT + tn];
    }

    // A: Xf[((bt*2+s)*2+kg)*7 + c]*4096 + jj*1024 + plane*512 + lane*8
    const __bf16* Ab = Xf + (size_t)bt * 114688 + (size_t)kg * 28672
                     + (size_t)jjh * 2048 + lane * 8;
    // B: wf[cg]*114688 + c*16384 + ((kg*4+jj)*4 + nt*2 + plane)*512 + lane*8
    const __bf16* Bbp = wf + (size_t)cg * 114688 + ((kg * 4 + jjh * 2) * 4) * 512
                      + lane * 8;

    f32x16 acc[2][2];   // [s][nt]
#pragma unroll
    for (int s = 0; s < 2; ++s)
#pragma unroll
        for (int nt = 0; nt < 2; ++nt)
#pragma unroll
            for (int r = 0; r < 16; ++r) acc[s][nt][r] = 0.0f;

    // register frags: A [s][j2] hi/lo, B [j2][nt] hi/lo; cur + next
    bf16x8 cAh[2][2], cAl[2][2], cBh[2][2], cBl[2][2];
    bf16x8 nAh[2][2], nAl[2][2], nBh[2][2], nBl[2][2];

#pragma unroll
    for (int s = 0; s < 2; ++s)
#pragma unroll
        for (int j2 = 0; j2 < 2; ++j2) {
            const __bf16* ap = Ab + s * 57344 + j2 * 1024;
            cAh[s][j2] = *(const bf16x8*)ap;
            cAl[s][j2] = *(const bf16x8*)(ap + 512);
        }
#pragma unroll
    for (int j2 = 0; j2 < 2; ++j2)
#pragma unroll
        for (int nt = 0; nt < 2; ++nt) {
            const __bf16* bp = Bbp + (j2 * 4 + nt * 2) * 512;
            cBh[j2][nt] = *(const bf16x8*)bp;
            cBl[j2][nt] = *(const bf16x8*)(bp + 512);
        }

#pragma unroll
    for (int c = 0; c < 7; ++c) {
        if (c < 6) {
            const __bf16* An = Ab + (c + 1) * 4096;
            const __bf16* Bn = Bbp + (c + 1) * 16384;
#pragma unroll
            for (int s = 0; s < 2; ++s)
#pragma unroll
                for (int j2 = 0; j2 < 2; ++j2) {
                    const __bf16* ap = An + s * 57344 + j2 * 1024;
                    nAh[s][j2] = *(const bf16x8*)ap;
                    nAl[s][j2] = *(const bf16x8*)(ap + 512);
                }
#pragma unroll
            for (int j2 = 0; j2 < 2; ++j2)
#pragma unroll
                for (int nt = 0; nt < 2; ++nt) {
                    const __bf16* bp = Bn + (j2 * 4 + nt * 2) * 512;
                    nBh[j2][nt] = *(const bf16x8*)bp;
                    nBl[j2][nt] = *(const bf16x8*)(bp + 512);
                }
        }
#pragma unroll
        for (int j2 = 0; j2 < 2; ++j2)
#pragma unroll
            for (int s = 0; s < 2; ++s)
#pragma unroll
                for (int nt = 0; nt < 2; ++nt) {
                    acc[s][nt] = __builtin_amdgcn_mfma_f32_32x32x16_bf16(
                        cAh[s][j2], cBh[j2][nt], acc[s][nt], 0, 0, 0);
                    acc[s][nt] = __builtin_amdgcn_mfma_f32_32x32x16_bf16(
                        cAh[s][j2], cBl[j2][nt], acc[s][nt], 0, 0, 0);
                    acc[s][nt] = __builtin_amdgcn_mfma_f32_32x32x16_bf16(
                        cAl[s][j2], cBh[j2][nt], acc[s][nt], 0, 0, 0);
                }
        if (c < 6) {
#pragma unroll
            for (int s = 0; s < 2; ++s)
#pragma unroll
                for (int j2 = 0; j2 < 2; ++j2) {
                    cAh[s][j2] = nAh[s][j2];
                    cAl[s][j2] = nAl[s][j2];
                }
#pragma unroll
            for (int j2 = 0; j2 < 2; ++j2)
#pragma unroll
                for (int nt = 0; nt < 2; ++nt) {
                    cBh[j2][nt] = nBh[j2][nt];
                    cBl[j2][nt] = nBl[j2][nt];
                }
        }
    }

    // ---- each wave writes its k-quarter partials to its zs plane ----
    float* zw = zs + w * (64 * ZSTR);
#pragma unroll
    for (int s = 0; s < 2; ++s)
#pragma unroll
        for (int nt = 0; nt < 2; ++nt)
#pragma unroll
            for (int r = 0; r < 16; ++r) {
                int rl = s * 32 + (r & 3) + ((r >> 2) << 3) + ((lane >> 5) << 2);
                zw[rl * ZSTR + nt * 32 + l31] = acc[s][nt][r];
            }
    __syncthreads();

    // ---- LSTM cell update: 64 rows x 16 h-cols = 1024 cells / 256 thr ----
    int hc16 = tid & 15;
    int hcol = (cg << 4) + hc16;
    float bi = bias[hcol], bj = bias[512 + hcol];
    float bfv = bias[1024 + hcol], bo = bias[1536 + hcol];
#pragma unroll
    for (int i = 0; i < 4; ++i) {
        int rl = i * 16 + (tid >> 4);
        int info = info_s[rl];
        int b = info & 511, sc = (info >> 15) & 1, sl = info >> 20;
        float zi = 0.f, zj = 0.f, zf = 0.f, zo = 0.f;
#pragma unroll
        for (int q = 0; q < 4; ++q) {
            const float* zp = zs + q * (64 * ZSTR) + rl * ZSTR;
            zi += zp[hc16];
            zj += zp[16 + hc16];
            zf += zp[32 + hc16];
            zo += zp[48 + hc16];
        }
        zi += bi; zj += bj; zf += bfv; zo += bo;
        size_t co = (size_t)(bt * 64 + rl) * HDIM + hcol;       // permuted
        size_t ho = (size_t)((sc << 9) + b) * HDIM + hcol;      // original
        float c_old = c_state[co];
        float h_old = h_state[ho];
        float nc = c_old * sigm(zf + 1.0f) + sigm(zi) * tanh_fast(zj);
        float nh = tanh_fast(nc) * sigm(zo);
        bool valid = t < sl;
        float cs = valid ? nc : c_old;
        float hs = valid ? nh : h_old;
        c_state[co] = cs;
        h_state[ho] = hs;
        __bf16 hh = (__bf16)hs;
        int grp = hc16 >> 3, e = hc16 & 7;
        zh[(grp * 64 + rl) * 8 + e] = hh;
        zh[((2 + grp) * 64 + rl) * 8 + e] = (__bf16)(hs - (float)hh);
    }
    __syncthreads();

    if (t + 1 < TT) {
        // h-part frag write to Xfn: 256 threads x 16B
        int plane = tid >> 7;
        int grp = (tid >> 6) & 1;
        int rl = tid & 63;
        bf16x8 val = *(const bf16x8*)(zh + ((plane * 2 + grp) * 64 + rl) * 8);
        int s2 = rl >> 5;
        int c2 = 3 + (cg >> 3);
        int kg2 = (cg >> 2) & 1;
        int jj2 = cg & 3;
        size_t base = ((((size_t)bt * 2 + s2) * 2 + kg2) * 7 + c2) * 4096
                    + jj2 * 1024 + plane * 512 + (grp * 32 + (rl & 31)) * 8;
        *(bf16x8*)(Xfn + base) = val;
        // embedding part of next step
        if (tid < 76) {
            int id = tid * 32 + cg;
            int rl2 = id / 38, rr = id - rl2 * 38;
            emb_unit(tk[rl2], rl2, rr, bt, emb, Xfn);
        }
    }
}

// ---------------------------------------------------------------------------
// Head stage 1: h_combined [512][2112] as bf16 hi/lo planes
// ---------------------------------------------------------------------------
__global__ __launch_bounds__(256) void head1(const float* __restrict__ h_state,
                                             const int* __restrict__ sl1,
                                             const int* __restrict__ sl2,
                                             __bf16* __restrict__ hch,
                                             __bf16* __restrict__ hcl) {
    int b = blockIdx.x;
    int tid = threadIdx.x;
    const float* h1 = h_state + (size_t)b * HDIM;
    const float* h2 = h_state + (size_t)(512 + b) * HDIM;
    size_t ro = (size_t)b * KP1;
    float l1 = (float)sl1[b] / (float)TT;
    float l2 = (float)sl2[b] / (float)TT;
    float part = 0.0f;
#pragma unroll
    for (int i = 0; i < 2; ++i) {
        int k = i * 256 + tid;
        float a = h1[k], c = h2[k];
        float sv = a - c;
        float mv = a * c;
        __bf16 xh;
        xh = (__bf16)a;  hch[ro + k] = xh;         hcl[ro + k] = (__bf16)(a - (float)xh);
        xh = (__bf16)c;  hch[ro + 513 + k] = xh;   hcl[ro + 513 + k] = (__bf16)(c - (float)xh);
        xh = (__bf16)sv; hch[ro + 1026 + k] = xh;  hcl[ro + 1026 + k] = (__bf16)(sv - (float)xh);
        xh = (__bf16)mv; hch[ro + 1540 + k] = xh;  hcl[ro + 1540 + k] = (__bf16)(mv - (float)xh);
        part += sv * sv;
    }
    __shared__ float red[4];
#pragma unroll
    for (int off = 32; off > 0; off >>= 1) part += __shfl_down(part, off, 64);
    if ((tid & 63) == 0) red[tid >> 6] = part;
    __syncthreads();
    if (tid == 0) {
        float d = red[0] + red[1] + red[2] + red[3];
        float ls = l1 - l2;
        d += ls * ls;
        float vals[5] = {l1, l2, ls, d, l1 * l2};
        int pos[5] = {512, 1025, 1538, 1539, 2052};
#pragma unroll
        for (int i = 0; i < 5; ++i) {
            __bf16 xh = (__bf16)vals[i];
            hch[ro + pos[i]] = xh;
            hcl[ro + pos[i]] = (__bf16)(vals[i] - (float)xh);
        }
    }
}

// ---------------------------------------------------------------------------
// Head stage 2 (MFMA): partials over 4 k-slices of 528
// ---------------------------------------------------------------------------
__global__ __launch_bounds__(512, 2) void head2m(
    const __bf16* __restrict__ hch, const __bf16* __restrict__ hcl,
    const __bf16* __restrict__ w1h, const __bf16* __restrict__ w1l,
    float* __restrict__ part) {

    __shared__ __align__(16) __bf16 Bb[2][64 * 512];

    int tid = threadIdx.x;
    int bx = blockIdx.x;
    int mt = bx >> 3;
    int n2 = (bx >> 2) & 1;
    int ks = bx & 3;
    int w = tid >> 6, lane = tid & 63, l31 = lane & 31;
    int half8 = (lane >> 5) << 3;
    int s = w >> 1, nh = w & 1;
    int kbase = ks * 528;

    int k8 = tid & 15;
    int jb = k8 >> 1;
    int rb = (tid >> 4) & 31;
    size_t gboff[8];
    int lo[8];
#pragma unroll
    for (int i = 0; i < 8; ++i) {
        int r = ((i & 3) << 5) + rb;
        int plane = i >> 2;
        int ng = n2 * 128 + r;
        gboff[i] = (size_t)ng * KP1 + k8 * 8;
        int nt = r >> 5;
        int colp = ((r & 31) + (jb << 2)) & 31;
        lo[i] = ((((jb << 2) + nt) << 1) + plane) * 512 + (colp + ((k8 & 1) << 5)) * 8;
    }

    const __bf16* Ah0 = hch + (size_t)(mt * 128 + s * 32 + l31) * KP1 + kbase + half8;
    const __bf16* Al0 = hcl + (size_t)(mt * 128 + s * 32 + l31) * KP1 + kbase + half8;

    bf16x8 rB[8];
    f32x16 acc[2];
#pragma unroll
    for (int nt = 0; nt < 2; ++nt)
#pragma unroll
        for (int r = 0; r < 16; ++r) acc[nt][r] = 0.0f;

#pragma unroll
    for (int i = 0; i < 8; ++i)
        rB[i] = *(const bf16x8*)(((i >= 4) ? w1l : w1h) + gboff[i] + kbase);
#pragma unroll
    for (int i = 0; i < 8; ++i) *(bf16x8*)(&Bb[0][lo[i]]) = rB[i];
    __syncthreads();

    for (int c = 0; c < 5; ++c) {
        int cur = c & 1;
        if (c < 4) {
            int k0 = kbase + (c + 1) * 128;
            bool tail = (c + 1 == 4);
#pragma unroll
            for (int i = 0; i < 8; ++i) {
                if (!tail || k8 < 2)
                    rB[i] = *(const bf16x8*)(((i >= 4) ? w1l : w1h) + gboff[i] + k0);
            }
        }
        int jmax = (c == 4) ? 1 : 8;
        for (int j = 0; j < jmax; ++j) {
            bf16x8 ah = *(const bf16x8*)(Ah0 + c * 128 + j * 16);
            bf16x8 al = *(const bf16x8*)(Al0 + c * 128 + j * 16);
            int cp = ((l31 + (j << 2)) & 31) + ((lane >> 5) << 5);
#pragma unroll
            for (int ntl = 0; ntl < 2; ++ntl) {
                int ntg = nh * 2 + ntl;
                const __bf16* bp = &Bb[cur][(((j << 2) + ntg) << 1) * 512 + cp * 8];
                bf16x8 bh = *(const bf16x8*)bp;
                bf16x8 bl = *(const bf16x8*)(bp + 512);
                acc[ntl] = __builtin_amdgcn_mfma_f32_32x32x16_bf16(ah, bh, acc[ntl], 0, 0, 0);
                acc[ntl] = __builtin_amdgcn_mfma_f32_32x32x16_bf16(ah, bl, acc[ntl], 0, 0, 0);
                acc[ntl] = __builtin_amdgcn_mfma_f32_32x32x16_bf16(al, bh, acc[ntl], 0, 0, 0);
            }
        }
        if (c < 4) {
#pragma unroll
            for (int i = 0; i < 8; ++i) *(bf16x8*)(&Bb[1 - cur][lo[i]]) = rB[i];
        }
        __syncthreads();
    }

#pragma unroll
    for (int ntl = 0; ntl < 2; ++ntl)
#pragma unroll
        for (int r = 0; r < 16; ++r) {
            int row = mt * 128 + s * 32 + (r & 3) + ((r >> 2) << 3) + ((lane >> 5) << 2);
            int col = n2 * 128 + nh * 64 + ntl * 32 + l31;
            part[((size_t)ks * 512 + row) * MDIM + col] = acc[ntl][r];
        }
}

// ---------------------------------------------------------------------------
// Head stage 3: e1 = relu(sum partials + b1); out = e1 @ W2 + b2
// ---------------------------------------------------------------------------
__global__ __launch_bounds__(256) void head3(const float* __restrict__ part,
                                             const float* __restrict__ b1,
                                             const float* __restrict__ W2,
                                             const float* __restrict__ b2,
                                             float* __restrict__ out) {
    int row = blockIdx.x;
    int tid = threadIdx.x;
    float sv = b1[tid];
#pragma unroll
    for (int ks = 0; ks < 4; ++ks)
        sv += part[((size_t)ks * 512 + row) * MDIM + tid];
    float e = fmaxf(sv, 0.0f);
    float p0 = e * W2[tid * 2 + 0];
    float p1 = e * W2[tid * 2 + 1];
#pragma unroll
    for (int off = 32; off > 0; off >>= 1) {
        p0 += __shfl_down(p0, off, 64);
        p1 += __shfl_down(p1, off, 64);
    }
    __shared__ float r0[4], r1[4];
    if ((tid & 63) == 0) { r0[tid >> 6] = p0; r1[tid >> 6] = p1; }
    __syncthreads();
    if (tid == 0) out[row * 2 + 0] = r0[0] + r0[1] + r0[2] + r0[3] + b2[0];
    if (tid == 1) out[row * 2 + 1] = r1[0] + r1[1] + r1[2] + r1[3] + b2[1];
}

// ---------------------------------------------------------------------------
extern "C" void kernel_launch(void* const* d_in, const int* in_sizes, int n_in,
                              void* d_out, int out_size, void* d_ws, size_t ws_size,
                              hipStream_t stream) {
    const int*   in1  = (const int*)d_in[0];
    const int*   in2  = (const int*)d_in[1];
    const int*   sl1  = (const int*)d_in[2];
    const int*   sl2  = (const int*)d_in[3];
    const float* emb  = (const float*)d_in[4];
    const float* kern = (const float*)d_in[5];
    const float* bias = (const float*)d_in[6];
    const float* W1   = (const float*)d_in[7];
    const float* b1   = (const float*)d_in[8];
    const float* W2   = (const float*)d_in[9];
    const float* b2   = (const float*)d_in[10];
    float* out = (float*)d_out;

    char* ws = (char*)d_ws;
    // ws layout (bytes):
    //   rowinfo i32[1024]         @ 0            (4096)
    //   nact u32[64]              @ 4096
    //   h_state f32 [1024*512]    @ 2,097,152    (2,097,152)
    //   c_state f32 [1024*512]    @ 4,194,304    (2,097,152)
    //   Xf0 bf16 frag             @ 6,291,456    (3,670,016)
    //   Xf1                       @ 9,961,472    (3,670,016)
    //   wf  bf16 frag             @ 13,631,488   (7,340,032)
    //   hch bf16 [512*2112]       @ 20,971,520   (2,162,688)
    //   hcl                       @ 23,134,208
    //   w1h bf16 [256*2112]       @ 25,296,896   (1,081,344)
    //   w1l                       @ 26,378,240
    //   part f32 [4*512*256]      @ 27,459,584   -> 29,556,736 total
    int*      rowinfo = (int*)ws;
    unsigned* nact    = (unsigned*)(ws + 4096u);
    float*  h_state = (float*)(ws + 2097152u);
    float*  c_state = (float*)(ws + 4194304u);
    __bf16* Xf0 = (__bf16*)(ws + 6291456u);
    __bf16* Xf1 = (__bf16*)(ws + 9961472u);
    __bf16* wf  = (__bf16*)(ws + 13631488u);
    __bf16* hch = (__bf16*)(ws + 20971520u);
    __bf16* hcl = (__bf16*)(ws + 23134208u);
    __bf16* w1h = (__bf16*)(ws + 25296896u);
    __bf16* w1l = (__bf16*)(ws + 26378240u);
    float*  part = (float*)(ws + 27459584u);

    // zero h_state, c_state, Xf0
    hipMemsetAsync(ws + 2097152u, 0, 7864320u, stream);
    // zero hch/hcl pad columns
    hipMemsetAsync(ws + 20971520u, 0, 4325376u, stream);

    sort_rows<<<dim3(1), dim3(256), 0, stream>>>(sl1, sl2, rowinfo, nact);
    prep_w<<<dim3(14 * 32), dim3(256), 0, stream>>>(kern, wf);
    prep_w1<<<dim3(33 * 4), dim3(256), 0, stream>>>(W1, w1h, w1l);
    prep_x0<<<dim3(512), dim3(256), 0, stream>>>(in1, in2, rowinfo, emb, Xf0);

    for (int t = 0; t < TT; ++t) {
        __bf16* Xf  = (t & 1) ? Xf1 : Xf0;
        __bf16* Xfn = (t & 1) ? Xf0 : Xf1;
        lstm_step<<<dim3(512), dim3(256), 0, stream>>>(
            t, in1, in2, rowinfo, nact, emb, bias, wf, Xf, Xfn,
            h_state, c_state);
    }

    head1<<<dim3(512), dim3(256), 0, stream>>>(h_state, sl1, sl2, hch, hcl);
    head2m<<<dim3(32), dim3(512), 0, stream>>>(hch, hcl, w1h, w1l, part);
    head3<<<dim3(512), dim3(256), 0, stream>>>(part, b1, W2, b2, out);
}

// Round 10
// 1069.661 us; speedup vs baseline: 1.0559x; 1.0559x over previous
//
#include <hip/hip_runtime.h>
#include <hip/hip_bf16.h>

// Problem constants
#define BATCH 512
#define TT 60
#define EDIM 300
#define HDIM 512
#define KREAL 812
#define KP 896           // 7 chunks of 128: emb k[0,300) pad[300,384) h k[384,896)
#define KP1 2112         // padded K for head GEMM (2053 -> 2112)
#define MDIM 256

typedef __bf16 bf16x4 __attribute__((ext_vector_type(4)));
typedef __bf16 bf16x8 __attribute__((ext_vector_type(8)));
typedef float  f32x16 __attribute__((ext_vector_type(16)));

#define GLL16(g, l) __builtin_amdgcn_global_load_lds( \
    (const __attribute__((address_space(1))) void*)(g), \
    (__attribute__((address_space(3))) void*)(l), 16, 0, 0)

__device__ __forceinline__ float sigm(float x) {
    return 1.0f / (1.0f + __expf(-x));
}
__device__ __forceinline__ float tanh_fast(float x) {
    float e = __expf(-2.0f * fabsf(x));
    float r = (1.0f - e) / (1.0f + e);
    return x >= 0.0f ? r : -r;
}

// ---------------------------------------------------------------------------
// Fragment layouts (bf16; a "slot" is lane*8 elems = 16B):
// Wf (weights): [cg:32][c:7][T:32][lane:64][e:8], T = j*4 + nt*2 + plane
// Xf (activations, 64-row tiles): [tile:16][s:2][kg:2][c:7][jj:4][plane:2][lane:64][e:8]
//   slot l of (tile,s,kg,c,jj,plane) = A[row = tile*64 + s*32 + (l&31)]
//                                       [k = c*128 + kg*64 + jj*16 + (l>>5)*8 + e]
// Rows are PERMUTED (sorted by seqlen desc): rowinfo[r] -> (src,b,sl).
// c_state at permuted index; h_state at ORIGINAL index (head1 reads unpermuted).
// XCD mapping (assumes round-robin blockIdx%8 -> XCD): each XCD gets
// 8 cg x 8 tiles -> working set 8x224KB B + 8x229KB A = 3.62 MB < 4 MB L2.
// Tiles parity-split across XCD pairs for early-exit load balance.
// ---------------------------------------------------------------------------

// Counting sort of the 1024 rows by seqlen descending; emits rowinfo and
// per-step active-tile counts nact[t] (64-row tiles).
__global__ __launch_bounds__(256) void sort_rows(const int* __restrict__ sl1,
                                                 const int* __restrict__ sl2,
                                                 int* __restrict__ rowinfo,
                                                 unsigned* __restrict__ nact) {
    __shared__ unsigned cnt[61];
    __shared__ unsigned off[61];
    int tid = threadIdx.x;
    if (tid < 61) cnt[tid] = 0;
    __syncthreads();
    for (int i = tid; i < 1024; i += 256) {
        int sl = (i < 512) ? sl1[i] : sl2[i - 512];
        atomicAdd(&cnt[60 - sl], 1u);
    }
    __syncthreads();
    if (tid == 0) {
        unsigned s = 0;
        for (int k = 0; k < 61; ++k) { off[k] = s; s += cnt[k]; }
        for (int t = 0; t < 60; ++t) {
            unsigned act = off[60 - t];        // #{sl > t}
            nact[t] = (act + 63) >> 6;
        }
    }
    __syncthreads();
    for (int i = tid; i < 1024; i += 256) {
        int sc = i >= 512;
        int b = i & 511;
        int sl = sc ? sl2[b] : sl1[b];
        unsigned pos = atomicAdd(&off[60 - sl], 1u);
        rowinfo[pos] = b | (sc << 15) | (sl << 20);
    }
}

// prep_w: lstm_kernel [812][2048] fp32 -> Wf (hi/lo split, k-remapped:
//   new k<300 -> kern k; 300..383 -> 0; >=384 -> kern k-84)
__global__ __launch_bounds__(256) void prep_w(const float* __restrict__ kern,
                                              __bf16* __restrict__ wf) {
    __shared__ float tile[64][65];
    int bk = blockIdx.x % 14;
    int bn = blockIdx.x / 14;
    int k0 = bk * 64, n0 = bn * 64;
    int tid = threadIdx.x;
#pragma unroll
    for (int i = 0; i < 16; ++i) {
        int id = i * 256 + tid;
        int kk = id >> 6, nn = id & 63;
        int kg = k0 + kk;
        int src = (kg < 300) ? kg : (kg >= 384 ? kg - 84 : -1);
        tile[kk][nn] = (src >= 0) ? kern[(size_t)src * 2048 + n0 + nn] : 0.0f;
    }
    __syncthreads();
    int gate = n0 >> 9;
    int nt = gate >> 1;
#pragma unroll
    for (int i = 0; i < 2; ++i) {
        int id = i * 256 + tid;          // 0..511 = nn(64) x k8(8)
        int nn = id >> 3, k8 = id & 7;
        bf16x8 hv, lv;
#pragma unroll
        for (int j = 0; j < 8; ++j) {
            float v = tile[k8 * 8 + j][nn];
            __bf16 h = (__bf16)v;
            hv[j] = h;
            lv[j] = (__bf16)(v - (float)h);
        }
        int cg = (((n0 & 511) >> 4) + (nn >> 4));
        int hc = nn & 15;
        int lzc = ((gate & 1) << 4) + hc;
        int kglob = k0 + k8 * 8;
        int c = kglob >> 7;
        int j = (kglob >> 4) & 7;
        int half = k8 & 1;
        size_t o = (size_t)cg * 114688 + c * 16384 + (j * 4 + nt * 2) * 512
                 + (half * 32 + lzc) * 8;
        *(bf16x8*)(wf + o) = hv;
        *(bf16x8*)(wf + o + 512) = lv;
    }
}

__global__ __launch_bounds__(256) void prep_w1(const float* __restrict__ W1,
                                               __bf16* __restrict__ w1h,
                                               __bf16* __restrict__ w1l) {
    __shared__ float tile[64][65];
    int bk = blockIdx.x % 33;
    int bn = blockIdx.x / 33;
    int k0 = bk * 64, n0 = bn * 64;
    int tid = threadIdx.x;
#pragma unroll
    for (int i = 0; i < 16; ++i) {
        int id = i * 256 + tid;
        int kk = id >> 6, nn = id & 63;
        int kg = k0 + kk;
        tile[kk][nn] = (kg < 2053) ? W1[(size_t)kg * MDIM + n0 + nn] : 0.0f;
    }
    __syncthreads();
#pragma unroll
    for (int i = 0; i < 2; ++i) {
        int id = i * 256 + tid;
        int nn = id >> 3, k8 = (id & 7) * 8;
        bf16x8 hv, lv;
#pragma unroll
        for (int j = 0; j < 8; ++j) {
            float v = tile[k8 + j][nn];
            __bf16 h = (__bf16)v;
            hv[j] = h;
            lv[j] = (__bf16)(v - (float)h);
        }
        size_t o = (size_t)(n0 + nn) * KP1 + k0 + k8;
        *(bf16x8*)(w1h + o) = hv;
        *(bf16x8*)(w1l + o) = lv;
    }
}

// Write one 8-elem embedding run (row rl in tile bt, run rr) into Xf frag layout
__device__ __forceinline__ void emb_unit(int tok, int rl, int rr, int bt,
                                         const float* __restrict__ emb,
                                         __bf16* Xfn) {
    const float* er = emb + (size_t)tok * EDIM + rr * 8;
    float4 f0 = *(const float4*)er;
    float4 f1 = (rr == 37) ? make_float4(0.f, 0.f, 0.f, 0.f)
                           : *(const float4*)(er + 4);
    float vv[8] = {f0.x, f0.y, f0.z, f0.w, f1.x, f1.y, f1.z, f1.w};
    bf16x8 hv, lv;
#pragma unroll
    for (int j = 0; j < 8; ++j) {
        __bf16 h = (__bf16)vv[j];
        hv[j] = h;
        lv[j] = (__bf16)(vv[j] - (float)h);
    }
    int ke = rr * 8;
    int c = ke >> 7, kl = ke & 127;
    int kg = kl >> 6, jj = (kl >> 4) & 3, half = (kl >> 3) & 1;
    int s = rl >> 5;
    size_t base = ((((size_t)bt * 2 + s) * 2 + kg) * 7 + c) * 4096 + jj * 1024
                + (half * 32 + (rl & 31)) * 8;
    *(bf16x8*)(Xfn + base) = hv;
    *(bf16x8*)(Xfn + base + 512) = lv;
}

// prep_x0: fill X0's embedding part (t=0, all tiles active). grid 512, 256 thr
__global__ __launch_bounds__(256) void prep_x0(const int* __restrict__ in1,
                                               const int* __restrict__ in2,
                                               const int* __restrict__ rowinfo,
                                               const float* __restrict__ emb,
                                               __bf16* __restrict__ Xf) {
    __shared__ int tk[64];
    int bt = blockIdx.x >> 5, cg = blockIdx.x & 31;
    int tid = threadIdx.x;
    if (tid < 64) {
        int info = rowinfo[bt * 64 + tid];
        int b = info & 511, sc = (info >> 15) & 1;
        tk[tid] = (sc ? in2 : in1)[b * TT];
    }
    __syncthreads();
    if (tid < 76) {
        int id = tid * 32 + cg;           // 0..2431 = 64 rows x 38 runs
        int rl = id / 38, rr = id - rl * 38;
        emb_unit(tk[rl], rl, rr, bt, emb, Xf);
    }
}

// ---------------------------------------------------------------------------
// One LSTM time step. grid 512 blocks x 256 thr = 16 tiles (64 rows) x 32 cg,
// 2 blocks/CU (64 KB LDS). XCD mapping: xcd = bx&7 gets 8 cg x 8 tiles
// (parity-split tiles) -> 3.62 MB working set, fully L2-resident.
// 4 waves = 2 m-strips x 2 k-groups; A direct from global (frag layout),
// B via global_load_lds double-buffer, 1 barrier per 128-k chunk.
// Tiles with no live rows (sorted by seqlen desc) early-exit via nact[t].
// ---------------------------------------------------------------------------
#define ZSTR 72

__global__ __launch_bounds__(256, 2) void lstm_step(
    int t,
    const int* __restrict__ in1, const int* __restrict__ in2,
    const int* __restrict__ rowinfo, const unsigned* __restrict__ nact,
    const float* __restrict__ emb, const float* __restrict__ bias,
    const __bf16* __restrict__ wf,
    const __bf16* __restrict__ Xf, __bf16* __restrict__ Xfn,
    float* __restrict__ h_state, float* __restrict__ c_state) {

    int bx = blockIdx.x;
    int xcd = bx & 7;
    int loc = bx >> 3;                     // 0..63
    int bt = ((loc >> 3) << 1) | (xcd & 1);          // parity-split tiles
    int cg = ((xcd >> 1) << 3) | (loc & 7);          // cg octet per xcd-pair
    if (bt >= (int)nact[t]) return;    // block-uniform early exit

    __shared__ __align__(16) __bf16 Bb[2][16384];   // 64 KB (zs/zh overlaid)
    __shared__ int info_s[64];
    __shared__ int tk[64];

    int tid = threadIdx.x;
    int w = tid >> 6, lane = tid & 63, l31 = lane & 31;
    int s = w >> 1, kg = w & 1;

    if (tid < 64) {
        int info = rowinfo[bt * 64 + tid];
        info_s[tid] = info;
        int b = info & 511, sc = (info >> 15) & 1;
        int tn = (t + 1 < TT) ? t + 1 : t;
        tk[tid] = (sc ? in2 : in1)[b * TT + tn];
    }

    const __bf16* wb = wf + (size_t)cg * 114688;
    auto stageB = [&](int c, int buf) {
        const __bf16* src = wb + c * 16384 + w * 4096 + lane * 8;
        __bf16* dst = &Bb[buf][w * 4096 + lane * 8];
#pragma unroll
        for (int i = 0; i < 8; ++i)
            GLL16(src + i * 512, dst + i * 512);
    };

    const __bf16* Abase = Xf + ((((size_t)bt * 2 + s) * 2 + kg) * 7) * 4096
                        + lane * 8;

    f32x16 acc[2];
#pragma unroll
    for (int nt = 0; nt < 2; ++nt)
#pragma unroll
        for (int r = 0; r < 16; ++r) acc[nt][r] = 0.0f;

    bf16x8 aH[4], aL[4];
    stageB(0, 0);
#pragma unroll
    for (int jj = 0; jj < 4; ++jj) {
        aH[jj] = *(const bf16x8*)(Abase + jj * 1024);
        aL[jj] = *(const bf16x8*)(Abase + jj * 1024 + 512);
    }
    __syncthreads();

#pragma unroll
    for (int c = 0; c < 7; ++c) {
        int cur = c & 1;
        bf16x8 nH[4], nL[4];
        if (c < 6) {
            stageB(c + 1, 1 - cur);
            const __bf16* An = Abase + (c + 1) * 4096;
#pragma unroll
            for (int jj = 0; jj < 4; ++jj) {
                nH[jj] = *(const bf16x8*)(An + jj * 1024);
                nL[jj] = *(const bf16x8*)(An + jj * 1024 + 512);
            }
        }
#pragma unroll
        for (int jj = 0; jj < 4; ++jj) {
            int j = kg * 4 + jj;
#pragma unroll
            for (int nt = 0; nt < 2; ++nt) {
                int T0 = (j * 4 + nt * 2) * 512 + lane * 8;
                bf16x8 bh = *(const bf16x8*)(&Bb[cur][T0]);
                bf16x8 bl = *(const bf16x8*)(&Bb[cur][T0 + 512]);
                acc[nt] = __builtin_amdgcn_mfma_f32_32x32x16_bf16(aH[jj], bh, acc[nt], 0, 0, 0);
                acc[nt] = __builtin_amdgcn_mfma_f32_32x32x16_bf16(aH[jj], bl, acc[nt], 0, 0, 0);
                acc[nt] = __builtin_amdgcn_mfma_f32_32x32x16_bf16(aL[jj], bh, acc[nt], 0, 0, 0);
            }
        }
        if (c < 6) {
#pragma unroll
            for (int jj = 0; jj < 4; ++jj) { aH[jj] = nH[jj]; aL[jj] = nL[jj]; }
        }
        __syncthreads();
    }

    // ---- split-k combine via zs overlay on Bb[1]: [64][ZSTR] f32 ----
    float* zs = (float*)&Bb[1][0];
    if (kg == 0) {
#pragma unroll
        for (int nt = 0; nt < 2; ++nt)
#pragma unroll
            for (int r = 0; r < 16; ++r) {
                int rl = s * 32 + (r & 3) + ((r >> 2) << 3) + ((lane >> 5) << 2);
                zs[rl * ZSTR + nt * 32 + l31] = acc[nt][r];
            }
    }
    __syncthreads();
    if (kg == 1) {
#pragma unroll
        for (int nt = 0; nt < 2; ++nt)
#pragma unroll
            for (int r = 0; r < 16; ++r) {
                int rl = s * 32 + (r & 3) + ((r >> 2) << 3) + ((lane >> 5) << 2);
                zs[rl * ZSTR + nt * 32 + l31] += acc[nt][r];
            }
    }
    __syncthreads();

    // ---- LSTM cell update: 64 rows x 16 h-cols = 1024 cells / 256 thr ----
    __bf16* zh = &Bb[0][0];    // [plane:2][grp:2][rl:64][e:8]
    int hc16 = tid & 15;
    int hcol = (cg << 4) + hc16;
    float bi = bias[hcol], bj = bias[512 + hcol];
    float bfv = bias[1024 + hcol], bo = bias[1536 + hcol];
#pragma unroll
    for (int i = 0; i < 4; ++i) {
        int rl = i * 16 + (tid >> 4);
        int info = info_s[rl];
        int b = info & 511, sc = (info >> 15) & 1, sl = info >> 20;
        float zi = zs[rl * ZSTR + hc16]      + bi;
        float zj = zs[rl * ZSTR + 16 + hc16] + bj;
        float zf = zs[rl * ZSTR + 32 + hc16] + bfv;
        float zo = zs[rl * ZSTR + 48 + hc16] + bo;
        size_t co = (size_t)(bt * 64 + rl) * HDIM + hcol;       // permuted
        size_t ho = (size_t)((sc << 9) + b) * HDIM + hcol;      // original
        float c_old = c_state[co];
        float h_old = h_state[ho];
        float nc = c_old * sigm(zf + 1.0f) + sigm(zi) * tanh_fast(zj);
        float nh = tanh_fast(nc) * sigm(zo);
        bool valid = t < sl;
        float cs = valid ? nc : c_old;
        float hs = valid ? nh : h_old;
        c_state[co] = cs;
        h_state[ho] = hs;
        __bf16 hh = (__bf16)hs;
        int grp = hc16 >> 3, e = hc16 & 7;
        zh[(grp * 64 + rl) * 8 + e] = hh;
        zh[((2 + grp) * 64 + rl) * 8 + e] = (__bf16)(hs - (float)hh);
    }
    __syncthreads();

    if (t + 1 < TT) {
        // h-part frag write to Xfn: 256 threads x 16B
        int plane = tid >> 7;
        int grp = (tid >> 6) & 1;
        int rl = tid & 63;
        bf16x8 val = *(const bf16x8*)(zh + ((plane * 2 + grp) * 64 + rl) * 8);
        int s2 = rl >> 5;
        int c2 = 3 + (cg >> 3);
        int kg2 = (cg >> 2) & 1;
        int jj2 = cg & 3;
        size_t base = ((((size_t)bt * 2 + s2) * 2 + kg2) * 7 + c2) * 4096
                    + jj2 * 1024 + plane * 512 + (grp * 32 + (rl & 31)) * 8;
        *(bf16x8*)(Xfn + base) = val;
        // embedding part of next step
        if (tid < 76) {
            int id = tid * 32 + cg;
            int rl2 = id / 38, rr = id - rl2 * 38;
            emb_unit(tk[rl2], rl2, rr, bt, emb, Xfn);
        }
    }
}

// ---------------------------------------------------------------------------
// Head stage 1: h_combined [512][2112] as bf16 hi/lo planes
// ---------------------------------------------------------------------------
__global__ __launch_bounds__(256) void head1(const float* __restrict__ h_state,
                                             const int* __restrict__ sl1,
                                             const int* __restrict__ sl2,
                                             __bf16* __restrict__ hch,
                                             __bf16* __restrict__ hcl) {
    int b = blockIdx.x;
    int tid = threadIdx.x;
    const float* h1 = h_state + (size_t)b * HDIM;
    const float* h2 = h_state + (size_t)(512 + b) * HDIM;
    size_t ro = (size_t)b * KP1;
    float l1 = (float)sl1[b] / (float)TT;
    float l2 = (float)sl2[b] / (float)TT;
    float part = 0.0f;
#pragma unroll
    for (int i = 0; i < 2; ++i) {
        int k = i * 256 + tid;
        float a = h1[k], c = h2[k];
        float sv = a - c;
        float mv = a * c;
        __bf16 xh;
        xh = (__bf16)a;  hch[ro + k] = xh;         hcl[ro + k] = (__bf16)(a - (float)xh);
        xh = (__bf16)c;  hch[ro + 513 + k] = xh;   hcl[ro + 513 + k] = (__bf16)(c - (float)xh);
        xh = (__bf16)sv; hch[ro + 1026 + k] = xh;  hcl[ro + 1026 + k] = (__bf16)(sv - (float)xh);
        xh = (__bf16)mv; hch[ro + 1540 + k] = xh;  hcl[ro + 1540 + k] = (__bf16)(mv - (float)xh);
        part += sv * sv;
    }
    __shared__ float red[4];
#pragma unroll
    for (int off = 32; off > 0; off >>= 1) part += __shfl_down(part, off, 64);
    if ((tid & 63) == 0) red[tid >> 6] = part;
    __syncthreads();
    if (tid == 0) {
        float d = red[0] + red[1] + red[2] + red[3];
        float ls = l1 - l2;
        d += ls * ls;
        float vals[5] = {l1, l2, ls, d, l1 * l2};
        int pos[5] = {512, 1025, 1538, 1539, 2052};
#pragma unroll
        for (int i = 0; i < 5; ++i) {
            __bf16 xh = (__bf16)vals[i];
            hch[ro + pos[i]] = xh;
            hcl[ro + pos[i]] = (__bf16)(vals[i] - (float)xh);
        }
    }
}

// ---------------------------------------------------------------------------
// Head stage 2 (MFMA): partials over 4 k-slices of 528
// ---------------------------------------------------------------------------
__global__ __launch_bounds__(512, 2) void head2m(
    const __bf16* __restrict__ hch, const __bf16* __restrict__ hcl,
    const __bf16* __restrict__ w1h, const __bf16* __restrict__ w1l,
    float* __restrict__ part) {

    __shared__ __align__(16) __bf16 Bb[2][64 * 512];

    int tid = threadIdx.x;
    int bx = blockIdx.x;
    int mt = bx >> 3;
    int n2 = (bx >> 2) & 1;
    int ks = bx & 3;
    int w = tid >> 6, lane = tid & 63, l31 = lane & 31;
    int half8 = (lane >> 5) << 3;
    int s = w >> 1, nh = w & 1;
    int kbase = ks * 528;

    int k8 = tid & 15;
    int jb = k8 >> 1;
    int rb = (tid >> 4) & 31;
    size_t gboff[8];
    int lo[8];
#pragma unroll
    for (int i = 0; i < 8; ++i) {
        int r = ((i & 3) << 5) + rb;
        int plane = i >> 2;
        int ng = n2 * 128 + r;
        gboff[i] = (size_t)ng * KP1 + k8 * 8;
        int nt = r >> 5;
        int colp = ((r & 31) + (jb << 2)) & 31;
        lo[i] = ((((jb << 2) + nt) << 1) + plane) * 512 + (colp + ((k8 & 1) << 5)) * 8;
    }

    const __bf16* Ah0 = hch + (size_t)(mt * 128 + s * 32 + l31) * KP1 + kbase + half8;
    const __bf16* Al0 = hcl + (size_t)(mt * 128 + s * 32 + l31) * KP1 + kbase + half8;

    bf16x8 rB[8];
    f32x16 acc[2];
#pragma unroll
    for (int nt = 0; nt < 2; ++nt)
#pragma unroll
        for (int r = 0; r < 16; ++r) acc[nt][r] = 0.0f;

#pragma unroll
    for (int i = 0; i < 8; ++i)
        rB[i] = *(const bf16x8*)(((i >= 4) ? w1l : w1h) + gboff[i] + kbase);
#pragma unroll
    for (int i = 0; i < 8; ++i) *(bf16x8*)(&Bb[0][lo[i]]) = rB[i];
    __syncthreads();

    for (int c = 0; c < 5; ++c) {
        int cur = c & 1;
        if (c < 4) {
            int k0 = kbase + (c + 1) * 128;
            bool tail = (c + 1 == 4);
#pragma unroll
            for (int i = 0; i < 8; ++i) {
                if (!tail || k8 < 2)
                    rB[i] = *(const bf16x8*)(((i >= 4) ? w1l : w1h) + gboff[i] + k0);
            }
        }
        int jmax = (c == 4) ? 1 : 8;
        for (int j = 0; j < jmax; ++j) {
            bf16x8 ah = *(const bf16x8*)(Ah0 + c * 128 + j * 16);
            bf16x8 al = *(const bf16x8*)(Al0 + c * 128 + j * 16);
            int cp = ((l31 + (j << 2)) & 31) + ((lane >> 5) << 5);
#pragma unroll
            for (int ntl = 0; ntl < 2; ++ntl) {
                int ntg = nh * 2 + ntl;
                const __bf16* bp = &Bb[cur][(((j << 2) + ntg) << 1) * 512 + cp * 8];
                bf16x8 bh = *(const bf16x8*)bp;
                bf16x8 bl = *(const bf16x8*)(bp + 512);
                acc[ntl] = __builtin_amdgcn_mfma_f32_32x32x16_bf16(ah, bh, acc[ntl], 0, 0, 0);
                acc[ntl] = __builtin_amdgcn_mfma_f32_32x32x16_bf16(ah, bl, acc[ntl], 0, 0, 0);
                acc[ntl] = __builtin_amdgcn_mfma_f32_32x32x16_bf16(al, bh, acc[ntl], 0, 0, 0);
            }
        }
        if (c < 4) {
#pragma unroll
            for (int i = 0; i < 8; ++i) *(bf16x8*)(&Bb[1 - cur][lo[i]]) = rB[i];
        }
        __syncthreads();
    }

#pragma unroll
    for (int ntl = 0; ntl < 2; ++ntl)
#pragma unroll
        for (int r = 0; r < 16; ++r) {
            int row = mt * 128 + s * 32 + (r & 3) + ((r >> 2) << 3) + ((lane >> 5) << 2);
            int col = n2 * 128 + nh * 64 + ntl * 32 + l31;
            part[((size_t)ks * 512 + row) * MDIM + col] = acc[ntl][r];
        }
}

// ---------------------------------------------------------------------------
// Head stage 3: e1 = relu(sum partials + b1); out = e1 @ W2 + b2
// ---------------------------------------------------------------------------
__global__ __launch_bounds__(256) void head3(const float* __restrict__ part,
                                             const float* __restrict__ b1,
                                             const float* __restrict__ W2,
                                             const float* __restrict__ b2,
                                             float* __restrict__ out) {
    int row = blockIdx.x;
    int tid = threadIdx.x;
    float sv = b1[tid];
#pragma unroll
    for (int ks = 0; ks < 4; ++ks)
        sv += part[((size_t)ks * 512 + row) * MDIM + tid];
    float e = fmaxf(sv, 0.0f);
    float p0 = e * W2[tid * 2 + 0];
    float p1 = e * W2[tid * 2 + 1];
#pragma unroll
    for (int off = 32; off > 0; off >>= 1) {
        p0 += __shfl_down(p0, off, 64);
        p1 += __shfl_down(p1, off, 64);
    }
    __shared__ float r0[4], r1[4];
    if ((tid & 63) == 0) { r0[tid >> 6] = p0; r1[tid >> 6] = p1; }
    __syncthreads();
    if (tid == 0) out[row * 2 + 0] = r0[0] + r0[1] + r0[2] + r0[3] + b2[0];
    if (tid == 1) out[row * 2 + 1] = r1[0] + r1[1] + r1[2] + r1[3] + b2[1];
}

// ---------------------------------------------------------------------------
extern "C" void kernel_launch(void* const* d_in, const int* in_sizes, int n_in,
                              void* d_out, int out_size, void* d_ws, size_t ws_size,
                              hipStream_t stream) {
    const int*   in1  = (const int*)d_in[0];
    const int*   in2  = (const int*)d_in[1];
    const int*   sl1  = (const int*)d_in[2];
    const int*   sl2  = (const int*)d_in[3];
    const float* emb  = (const float*)d_in[4];
    const float* kern = (const float*)d_in[5];
    const float* bias = (const float*)d_in[6];
    const float* W1   = (const float*)d_in[7];
    const float* b1   = (const float*)d_in[8];
    const float* W2   = (const float*)d_in[9];
    const float* b2   = (const float*)d_in[10];
    float* out = (float*)d_out;

    char* ws = (char*)d_ws;
    // ws layout (bytes):
    //   rowinfo i32[1024]         @ 0            (4096)
    //   nact u32[64]              @ 4096
    //   h_state f32 [1024*512]    @ 2,097,152    (2,097,152)
    //   c_state f32 [1024*512]    @ 4,194,304    (2,097,152)
    //   Xf0 bf16 frag             @ 6,291,456    (3,670,016)
    //   Xf1                       @ 9,961,472    (3,670,016)
    //   wf  bf16 frag             @ 13,631,488   (7,340,032)
    //   hch bf16 [512*2112]       @ 20,971,520   (2,162,688)
    //   hcl                       @ 23,134,208
    //   w1h bf16 [256*2112]       @ 25,296,896   (1,081,344)
    //   w1l                       @ 26,378,240
    //   part f32 [4*512*256]      @ 27,459,584   -> 29,556,736 total
    int*      rowinfo = (int*)ws;
    unsigned* nact    = (unsigned*)(ws + 4096u);
    float*  h_state = (float*)(ws + 2097152u);
    float*  c_state = (float*)(ws + 4194304u);
    __bf16* Xf0 = (__bf16*)(ws + 6291456u);
    __bf16* Xf1 = (__bf16*)(ws + 9961472u);
    __bf16* wf  = (__bf16*)(ws + 13631488u);
    __bf16* hch = (__bf16*)(ws + 20971520u);
    __bf16* hcl = (__bf16*)(ws + 23134208u);
    __bf16* w1h = (__bf16*)(ws + 25296896u);
    __bf16* w1l = (__bf16*)(ws + 26378240u);
    float*  part = (float*)(ws + 27459584u);

    // zero h_state, c_state, Xf0
    hipMemsetAsync(ws + 2097152u, 0, 7864320u, stream);
    // zero hch/hcl pad columns
    hipMemsetAsync(ws + 20971520u, 0, 4325376u, stream);

    sort_rows<<<dim3(1), dim3(256), 0, stream>>>(sl1, sl2, rowinfo, nact);
    prep_w<<<dim3(14 * 32), dim3(256), 0, stream>>>(kern, wf);
    prep_w1<<<dim3(33 * 4), dim3(256), 0, stream>>>(W1, w1h, w1l);
    prep_x0<<<dim3(512), dim3(256), 0, stream>>>(in1, in2, rowinfo, emb, Xf0);

    for (int t = 0; t < TT; ++t) {
        __bf16* Xf  = (t & 1) ? Xf1 : Xf0;
        __bf16* Xfn = (t & 1) ? Xf0 : Xf1;
        lstm_step<<<dim3(512), dim3(256), 0, stream>>>(
            t, in1, in2, rowinfo, nact, emb, bias, wf, Xf, Xfn,
            h_state, c_state);
    }

    head1<<<dim3(512), dim3(256), 0, stream>>>(h_state, sl1, sl2, hch, hcl);
    head2m<<<dim3(32), dim3(512), 0, stream>>>(hch, hcl, w1h, w1l, part);
    head3<<<dim3(512), dim3(256), 0, stream>>>(part, b1, W2, b2, out);
}